// Round 3
// baseline (512.716 us; speedup 1.0000x reference)
//
#include <hip/hip_runtime.h>

#define TS    256
#define ROWS  16
#define DIN   28

typedef _Float16 f16x8 __attribute__((ext_vector_type(8)));
typedef float    f32x4 __attribute__((ext_vector_type(4)));

#if __has_builtin(__builtin_amdgcn_rcpf)
#define RCPF(x) __builtin_amdgcn_rcpf(x)
#else
#define RCPF(x) (1.0f / (x))
#endif
#if __has_builtin(__builtin_amdgcn_exp2f)
#define EXP2F(x) __builtin_amdgcn_exp2f(x)
#else
#define EXP2F(x) exp2f(x)
#endif

__device__ __forceinline__ float sigm(float x) {
  return RCPF(1.0f + EXP2F(x * -1.44269504f));
}
__device__ __forceinline__ float tanhf_(float x) {
  return 1.0f - 2.0f * RCPF(1.0f + EXP2F(x * 2.885390082f));
}
__device__ __forceinline__ f16x8 cvt8(float4 a, float4 b) {
  f16x8 r;
  r[0] = (_Float16)a.x; r[1] = (_Float16)a.y; r[2] = (_Float16)a.z; r[3] = (_Float16)a.w;
  r[4] = (_Float16)b.x; r[5] = (_Float16)b.y; r[6] = (_Float16)b.z; r[7] = (_Float16)b.w;
  return r;
}

#define MFMA32(a, b, c) __builtin_amdgcn_mfma_f32_16x16x32_f16((a), (b), (c), 0, 0, 0)

__device__ __forceinline__ int imin(int a, int b) { return a < b ? a : b; }

// spin until all 4 waves of a group have flag >= T (flags monotonic in t)
__device__ __forceinline__ void wait4(volatile int* f, int T) {
  int a = f[0], b = f[1], c = f[2], d = f[3];
  while (imin(imin(a, b), imin(c, d)) < T) {
    __builtin_amdgcn_s_sleep(1);
    a = f[0]; b = f[1]; c = f[2]; d = f[3];
  }
}

// Barrier-free diagonal pipeline: 1024-thread block = 4 layer-groups x 4
// col-waves. No __syncthreads in the main loop: per-(layer,step) LDS flags
// (release store / acquire spin) with a ring of 4 h-buffers (slot = t & 3).
// Group l step t waits on: own group done t-1 (recurrence), group l-1 done t
// (input), group l+1 done t-4 (anti-overwrite back-pressure). Acyclic in
// (l,t) and all 16 waves co-resident -> deadlock-free.
__global__ __launch_bounds__(1024, 4) void lstm4_flags(
    const float* __restrict__ x,
    const float* __restrict__ Wih0, const float* __restrict__ Whh0,
    const float* __restrict__ bih0, const float* __restrict__ bhh0,
    const float* __restrict__ Wih1, const float* __restrict__ Whh1,
    const float* __restrict__ bih1, const float* __restrict__ bhh1,
    const float* __restrict__ Wih2, const float* __restrict__ Whh2,
    const float* __restrict__ bih2, const float* __restrict__ bhh2,
    const float* __restrict__ Wih3, const float* __restrict__ Whh3,
    const float* __restrict__ bih3, const float* __restrict__ bhh3,
    const float* __restrict__ Wout, const float* __restrict__ bout,
    float* __restrict__ out)
{
  const int tid  = (int)threadIdx.x;
  const int lane = tid & 63;
  const int w    = tid >> 6;   // wave 0..15
  const int l    = w >> 2;     // layer group 0..3
  const int wv   = w & 3;      // col tile -> h cols [16wv,16wv+16)
  const int r    = lane & 15;  // A-row (batch row) / B-col (h col in tile)
  const int q    = lane >> 4;  // quarter group -> k positions 8q+i
  const int r0   = (int)blockIdx.x * ROWS;

  __shared__ _Float16 hbuf[4][4][ROWS][72] __attribute__((aligned(16)));  // [layer][t&3][row][col]
  __shared__ int flags[4][4][4] __attribute__((aligned(16)));             // [layer][t&3][wave] = last t done

  for (int i = tid; i < 4 * 4 * ROWS * 72; i += 1024)
    (&hbuf[0][0][0][0])[i] = (_Float16)0.0f;
  if (tid < 64) (&flags[0][0][0])[tid] = -1;
  __syncthreads();

  const float* Wih = (l == 0) ? Wih0 : (l == 1) ? Wih1 : (l == 2) ? Wih2 : Wih3;
  const float* Whh = (l == 0) ? Whh0 : (l == 1) ? Whh1 : (l == 2) ? Whh2 : Whh3;
  const float* bih = (l == 0) ? bih0 : (l == 1) ? bih1 : (l == 2) ? bih2 : bih3;
  const float* bhh = (l == 0) ? bhh0 : (l == 1) ? bhh1 : (l == 2) ? bhh2 : bhh3;

  // B-fragments (k position = koff + 8q + i, consistent with A packing)
  f16x8 wx[4][2];  // input weights: l=0 -> 1 ktile (K=28 pad 32); l>0 -> 2 ktiles
  f16x8 wh[4][2];  // recurrent weights, K=64 -> 2 ktiles
  float bv[4];

#pragma unroll
  for (int nt = 0; nt < 4; ++nt) {  // gate 0=i 1=f 2=g 3=o
    const int col = 64 * nt + 16 * wv + r;
    if (l == 0) {
      const float4 a = *(const float4*)&Wih[col * DIN + 8 * q];
      float4 b = make_float4(0.f, 0.f, 0.f, 0.f);
      if (q < 3) b = *(const float4*)&Wih[col * DIN + 8 * q + 4];
      wx[nt][0] = cvt8(a, b);
      wx[nt][1] = cvt8(make_float4(0, 0, 0, 0), make_float4(0, 0, 0, 0));
    } else {
#pragma unroll
      for (int kt = 0; kt < 2; ++kt)
        wx[nt][kt] = cvt8(*(const float4*)&Wih[col * 64 + kt * 32 + 8 * q],
                          *(const float4*)&Wih[col * 64 + kt * 32 + 8 * q + 4]);
    }
#pragma unroll
    for (int kt = 0; kt < 2; ++kt)
      wh[nt][kt] = cvt8(*(const float4*)&Whh[col * 64 + kt * 32 + 8 * q],
                        *(const float4*)&Whh[col * 64 + kt * 32 + 8 * q + 4]);
    bv[nt] = bih[col] + bhh[col];
  }

  // layer-0 x A-fragment: x[r0+r][t][8q+i], k>=28 zero-padded
  const float* xrow = x + (size_t)(r0 + r) * (TS * DIN);
  f16x8 xa = cvt8(make_float4(0, 0, 0, 0), make_float4(0, 0, 0, 0));
  if (l == 0) {
    const float4 a = *(const float4*)&xrow[8 * q];
    float4 b = make_float4(0.f, 0.f, 0.f, 0.f);
    if (q < 3) b = *(const float4*)&xrow[8 * q + 4];
    xa = cvt8(a, b);
  }

  f32x4 cst = f32x4{0.f, 0.f, 0.f, 0.f};

  for (int t = 0; t < TS; ++t) {
    const int sl = t & 3, sp = (t - 1) & 3;

    // issue next x loads early (HBM latency overlaps spins + MFMA)
    float4 nx0 = make_float4(0, 0, 0, 0), nx1 = make_float4(0, 0, 0, 0);
    if (l == 0 && t + 1 < TS) {
      nx0 = *(const float4*)&xrow[(t + 1) * DIN + 8 * q];
      if (q < 3) nx1 = *(const float4*)&xrow[(t + 1) * DIN + 8 * q + 4];
    }

    if (l < 3) wait4(&flags[l + 1][sl][0], t - 4);  // anti-overwrite
    if (l > 0) wait4(&flags[l - 1][sl][0], t);      // input ready
    wait4(&flags[l][sp][0], t - 1);                 // recurrence ready
    __threadfence_block();

    f32x4 acc[4];
#pragma unroll
    for (int nt = 0; nt < 4; ++nt)
      acc[nt] = f32x4{bv[nt], bv[nt], bv[nt], bv[nt]};

    const _Float16* prc = &hbuf[l][sp][r][8 * q];
    const f16x8 arc0 = *(const f16x8*)(prc);
    const f16x8 arc1 = *(const f16x8*)(prc + 32);

    if (l == 0) {
#pragma unroll
      for (int nt = 0; nt < 4; ++nt) {
        acc[nt] = MFMA32(xa, wx[nt][0], acc[nt]);
        acc[nt] = MFMA32(arc0, wh[nt][0], acc[nt]);
        acc[nt] = MFMA32(arc1, wh[nt][1], acc[nt]);
      }
      xa = cvt8(nx0, nx1);
    } else {
      const _Float16* pin = &hbuf[l - 1][sl][r][8 * q];
      const f16x8 ain0 = *(const f16x8*)(pin);
      const f16x8 ain1 = *(const f16x8*)(pin + 32);
#pragma unroll
      for (int nt = 0; nt < 4; ++nt) {
        acc[nt] = MFMA32(ain0, wx[nt][0], acc[nt]);
        acc[nt] = MFMA32(ain1, wx[nt][1], acc[nt]);
        acc[nt] = MFMA32(arc0, wh[nt][0], acc[nt]);
        acc[nt] = MFMA32(arc1, wh[nt][1], acc[nt]);
      }
    }

    _Float16* pw = &hbuf[l][sl][4 * q][16 * wv + r];
#pragma unroll
    for (int j = 0; j < 4; ++j) {
      const float ig = sigm(acc[0][j]);
      const float fg = sigm(acc[1][j]);
      const float gg = tanhf_(acc[2][j]);
      const float og = sigm(acc[3][j]);
      const float c  = fg * cst[j] + ig * gg;
      cst[j] = c;
      pw[j * 72] = (_Float16)(og * tanhf_(c));
    }

    if (lane == 0)
      __hip_atomic_store(&flags[l][sl][wv], t, __ATOMIC_RELEASE, __HIP_MEMORY_SCOPE_WORKGROUP);
  }

  __syncthreads();

  // h3_255 lives in slot 255 & 3 = 3
  if (tid < 160) {
    const int rr = tid & 15;
    const int oc = tid >> 4;
    float a = bout[oc];
#pragma unroll 16
    for (int k = 0; k < 64; ++k)
      a += (float)hbuf[3][3][rr][k] * Wout[oc * 64 + k];
    out[(size_t)(r0 + rr) * 10 + oc] = a;
  }
}

extern "C" void kernel_launch(void* const* d_in, const int* in_sizes, int n_in,
                              void* d_out, int out_size, void* d_ws, size_t ws_size,
                              hipStream_t stream) {
  (void)in_sizes; (void)n_in; (void)d_ws; (void)ws_size; (void)out_size;
  lstm4_flags<<<dim3(4096 / ROWS), dim3(1024), 0, stream>>>(
      (const float*)d_in[0],
      (const float*)d_in[1],  (const float*)d_in[2],  (const float*)d_in[3],  (const float*)d_in[4],
      (const float*)d_in[5],  (const float*)d_in[6],  (const float*)d_in[7],  (const float*)d_in[8],
      (const float*)d_in[9],  (const float*)d_in[10], (const float*)d_in[11], (const float*)d_in[12],
      (const float*)d_in[13], (const float*)d_in[14], (const float*)d_in[15], (const float*)d_in[16],
      (const float*)d_in[17], (const float*)d_in[18],
      (float*)d_out);
}